// Round 1
// baseline (25588.695 us; speedup 1.0000x reference)
//
#include <hip/hip_runtime.h>
#include <math.h>

#define BB 32      // batch
#define SS 64      // source length
#define HH 1024    // hidden
#define VV 32000   // vocab
#define NSTEPS 64  // decode steps

__device__ __forceinline__ float sigmoidf_(float x) { return 1.0f / (1.0f + expf(-x)); }

// ---------------- init h,c = 0 ----------------
__global__ void init_hc(float* __restrict__ h, float* __restrict__ c) {
    int i = blockIdx.x * 256 + threadIdx.x;
    if (i < BB * HH) { h[i] = 0.f; c[i] = 0.f; }
}

// ---------------- skinny GEMM: out[ks][b][n] = sum_{k in slice ks} A[b][k] * W[k][n] ----------------
// A row = [A1row (1024) | A2row (1024)]; A1 row either direct or emb[tok[b]] gather.
// W row k: k < KW1 -> W1[k], else W2[k-KW1]. Each thread: 32 batch accs x 2 cols (float2).
template <int KS>
__global__ __launch_bounds__(256) void gemm_skinny(
    const float* __restrict__ A1, const float* __restrict__ A2,
    const int* __restrict__ tok, int tok_stride, const float* __restrict__ emb,
    const float* __restrict__ W1, const float* __restrict__ W2, int KW1,
    int N, int jblocks, float* __restrict__ outp)
{
    __shared__ alignas(16) float At[KS][36];  // [k][b], padded: 144B rows (16B aligned)
    const int tid = threadIdx.x;
    const int jb = blockIdx.x % jblocks;
    const int ks = blockIdx.x / jblocks;
    const int k0 = ks * KS;

    // stage A[k0..k0+KS) for all 32 b; consecutive tid -> consecutive k (coalesced per b-row)
    for (int i = tid; i < KS * BB; i += 256) {
        int b = i / KS;
        int k = i % KS;
        int kg = k0 + k;
        float v;
        if (kg < 1024) {
            const float* r = A1 ? (A1 + (size_t)b * 1024)
                                : (emb + (size_t)tok[b * tok_stride] * 1024);
            v = r[kg];
        } else {
            v = A2[(size_t)b * 1024 + (kg - 1024)];
        }
        At[k][b] = v;
    }
    __syncthreads();

    const int jj = jb * 256 + tid;  // float2 column-pair index
    if (2 * jj >= N) return;
    const float* Wbase = (k0 < KW1) ? (W1 + (size_t)k0 * N)
                                    : (W2 + (size_t)(k0 - KW1) * N);
    float2 acc[BB];
#pragma unroll
    for (int b = 0; b < BB; b++) { acc[b].x = 0.f; acc[b].y = 0.f; }

#pragma unroll 1
    for (int k = 0; k < KS; k++) {
        const float2 w = *(const float2*)(Wbase + (size_t)k * N + 2 * jj);
#pragma unroll
        for (int b = 0; b < BB; b += 4) {
            const float4 a = *(const float4*)&At[k][b];  // LDS broadcast b128
            acc[b + 0].x = fmaf(a.x, w.x, acc[b + 0].x); acc[b + 0].y = fmaf(a.x, w.y, acc[b + 0].y);
            acc[b + 1].x = fmaf(a.y, w.x, acc[b + 1].x); acc[b + 1].y = fmaf(a.y, w.y, acc[b + 1].y);
            acc[b + 2].x = fmaf(a.z, w.x, acc[b + 2].x); acc[b + 2].y = fmaf(a.z, w.y, acc[b + 2].y);
            acc[b + 3].x = fmaf(a.w, w.x, acc[b + 3].x); acc[b + 3].y = fmaf(a.w, w.y, acc[b + 3].y);
        }
    }
#pragma unroll
    for (int b = 0; b < BB; b++) {
        *(float2*)(outp + ((size_t)ks * BB + b) * N + 2 * jj) = acc[b];
    }
}

// ---------------- encoder gates: reduce z partials, LSTM cell, write h,c,hs[:,s,:] ----------------
__global__ __launch_bounds__(256) void enc_gates(
    const float* __restrict__ zpart, int nslices, const float* __restrict__ bias,
    float* __restrict__ h, float* __restrict__ c, float* __restrict__ hs, int s)
{
    int idx = blockIdx.x * 256 + threadIdx.x;  // 32768
    int b = idx >> 10, j = idx & 1023;
    float zi = bias[j], zf = bias[1024 + j], zg = bias[2048 + j], zo = bias[3072 + j];
    for (int ks = 0; ks < nslices; ks++) {
        const float* zp = zpart + ((size_t)ks * BB + b) * 4096;
        zi += zp[j]; zf += zp[1024 + j]; zg += zp[2048 + j]; zo += zp[3072 + j];
    }
    float cp = c[idx];
    float c2 = sigmoidf_(zf) * cp + sigmoidf_(zi) * tanhf(zg);
    float h2 = sigmoidf_(zo) * tanhf(c2);
    c[idx] = c2; h[idx] = h2;
    hs[((size_t)b * SS + s) * HH + j] = h2;
}

// ---------------- hs_a = hs @ W_a  (2048x1024 @ 1024x1024), + y := BOS ----------------
__global__ __launch_bounds__(256) void hsa_kernel(
    const float* __restrict__ hs, const float* __restrict__ W_a,
    float* __restrict__ hs_a, int* __restrict__ y)
{
    if (blockIdx.x == 0 && threadIdx.x < BB) y[threadIdx.x] = 1;  // BOS
    __shared__ alignas(16) float At[64][12];  // [k][r], 48B rows (16B aligned)
    const int tid = threadIdx.x;
    const int rg = blockIdx.x & 255;   // rowgroup of 8 rows (256 groups)
    const int jpb = blockIdx.x >> 8;   // 0..1
    const int jj = jpb * 256 + tid;    // pair col in [0,512)
    float2 acc[8];
#pragma unroll
    for (int r = 0; r < 8; r++) { acc[r].x = 0.f; acc[r].y = 0.f; }

    for (int kc = 0; kc < 1024; kc += 64) {
        __syncthreads();
        for (int i = tid; i < 512; i += 256) {
            int r = i >> 6, k = i & 63;
            At[k][r] = hs[(size_t)(rg * 8 + r) * 1024 + kc + k];
        }
        __syncthreads();
#pragma unroll 1
        for (int k = 0; k < 64; k++) {
            float2 w = *(const float2*)(W_a + (size_t)(kc + k) * 1024 + 2 * jj);
            float4 a0 = *(const float4*)&At[k][0];
            float4 a1 = *(const float4*)&At[k][4];
            acc[0].x = fmaf(a0.x, w.x, acc[0].x); acc[0].y = fmaf(a0.x, w.y, acc[0].y);
            acc[1].x = fmaf(a0.y, w.x, acc[1].x); acc[1].y = fmaf(a0.y, w.y, acc[1].y);
            acc[2].x = fmaf(a0.z, w.x, acc[2].x); acc[2].y = fmaf(a0.z, w.y, acc[2].y);
            acc[3].x = fmaf(a0.w, w.x, acc[3].x); acc[3].y = fmaf(a0.w, w.y, acc[3].y);
            acc[4].x = fmaf(a1.x, w.x, acc[4].x); acc[4].y = fmaf(a1.x, w.y, acc[4].y);
            acc[5].x = fmaf(a1.y, w.x, acc[5].x); acc[5].y = fmaf(a1.y, w.y, acc[5].y);
            acc[6].x = fmaf(a1.z, w.x, acc[6].x); acc[6].y = fmaf(a1.z, w.y, acc[6].y);
            acc[7].x = fmaf(a1.w, w.x, acc[7].x); acc[7].y = fmaf(a1.w, w.y, acc[7].y);
        }
    }
#pragma unroll
    for (int r = 0; r < 8; r++)
        *(float2*)(hs_a + (size_t)(rg * 8 + r) * 1024 + 2 * jj) = acc[r];
}

// ---------------- decoder: gates (+mask) then attention (scores/softmax/ctx). one block per b ----------------
__global__ __launch_bounds__(256) void attn_gates(
    const float* __restrict__ zpart, int nslices, const float* __restrict__ bias,
    const int* __restrict__ y, float* __restrict__ h, float* __restrict__ c,
    const float* __restrict__ hs_a, const float* __restrict__ hs,
    const int* __restrict__ source, float* __restrict__ ctx)
{
    __shared__ alignas(16) float h2s[HH];
    __shared__ float red[256];
    __shared__ float av[SS];
    const int b = blockIdx.x, tid = threadIdx.x;
    const bool m = (y[b] != 0);

    for (int u = 0; u < 4; u++) {
        int j = tid + 256 * u;
        float zi = bias[j], zf = bias[1024 + j], zg = bias[2048 + j], zo = bias[3072 + j];
        for (int ks = 0; ks < nslices; ks++) {
            const float* zp = zpart + ((size_t)ks * BB + b) * 4096;
            zi += zp[j]; zf += zp[1024 + j]; zg += zp[2048 + j]; zo += zp[3072 + j];
        }
        int idx = b * HH + j;
        float cp = c[idx], hp = h[idx];
        float c2 = sigmoidf_(zf) * cp + sigmoidf_(zi) * tanhf(zg);
        float h2 = sigmoidf_(zo) * tanhf(c2);
        if (!m) { c2 = cp; h2 = hp; }
        c[idx] = c2; h[idx] = h2; h2s[j] = h2;
    }
    __syncthreads();

    // scores: 64 t-lanes x 4 k-chunks of 256
    {
        int t = tid & 63, kc = tid >> 6;
        const float4* row = (const float4*)(hs_a + ((size_t)b * SS + t) * HH) + kc * 64;
        const float4* hv = (const float4*)h2s + kc * 64;
        float sc = 0.f;
#pragma unroll 4
        for (int i = 0; i < 64; i++) {
            float4 a = row[i], x = hv[i];
            sc += a.x * x.x + a.y * x.y + a.z * x.z + a.w * x.w;
        }
        red[tid] = sc;
    }
    __syncthreads();
    if (tid < 64) {
        float s = red[tid] + red[tid + 64] + red[tid + 128] + red[tid + 192];
        if (source[b * SS + tid] == 0) s = -1e9f;
        red[tid] = s;
    }
    __syncthreads();
    if (tid < 64) {
        float mx = -3.4e38f;
        for (int i = 0; i < 64; i++) mx = fmaxf(mx, red[i]);
        av[tid] = expf(red[tid] - mx);
    }
    __syncthreads();
    if (tid < 64) {  // single wave: all loads precede the store in program order
        float ssum = 0.f;
        for (int i = 0; i < 64; i++) ssum += av[i];
        av[tid] = av[tid] / ssum;
    }
    __syncthreads();
    // ctx[j] = sum_t a[t] * hs[b][t][j]
    for (int u = 0; u < 4; u++) {
        int j = tid + 256 * u;
        float s = 0.f;
        for (int t = 0; t < SS; t++) s += av[t] * hs[((size_t)b * SS + t) * HH + j];
        ctx[b * HH + j] = s;
    }
}

// ---------------- ht = tanh(reduce(wcpart) + b_c) ----------------
__global__ __launch_bounds__(256) void ht_reduce(
    const float* __restrict__ wcpart, int nslices,
    const float* __restrict__ b_c, float* __restrict__ ht)
{
    int idx = blockIdx.x * 256 + threadIdx.x;  // 32768
    int b = idx >> 10, j = idx & 1023;
    float s = b_c[j];
    for (int ks = 0; ks < nslices; ks++) s += wcpart[((size_t)ks * BB + b) * HH + j];
    ht[idx] = tanhf(s);
}

// ---------------- softmax over V, write probs to out[b][step][:], y[b]=argmax ----------------
__global__ __launch_bounds__(256) void softmax_out(
    const float* __restrict__ lpart,  // [4][B][V]
    const float* __restrict__ b_out, float* __restrict__ lrow,
    float* __restrict__ out, int* __restrict__ y, int step)
{
    __shared__ float rv[256];
    __shared__ int ri[256];
    __shared__ float rs[256];
    const int b = blockIdx.x, tid = threadIdx.x;
    float bmax = -3.4e38f; int barg = 0;
    for (int v = tid; v < VV; v += 256) {
        float l = b_out[v];
        l += lpart[((size_t)0 * BB + b) * VV + v];
        l += lpart[((size_t)1 * BB + b) * VV + v];
        l += lpart[((size_t)2 * BB + b) * VV + v];
        l += lpart[((size_t)3 * BB + b) * VV + v];
        lrow[(size_t)b * VV + v] = l;
        if (l > bmax) { bmax = l; barg = v; }  // strict > keeps lowest index per thread
    }
    rv[tid] = bmax; ri[tid] = barg;
    __syncthreads();
    for (int off = 128; off > 0; off >>= 1) {
        if (tid < off) {
            float v2 = rv[tid + off]; int i2 = ri[tid + off];
            if (v2 > rv[tid] || (v2 == rv[tid] && i2 < ri[tid])) { rv[tid] = v2; ri[tid] = i2; }
        }
        __syncthreads();
    }
    const float mx = rv[0];
    float ls = 0.f;
    for (int v = tid; v < VV; v += 256) ls += expf(lrow[(size_t)b * VV + v] - mx);
    rs[tid] = ls;
    __syncthreads();
    for (int off = 128; off > 0; off >>= 1) {
        if (tid < off) rs[tid] += rs[tid + off];
        __syncthreads();
    }
    const float inv = 1.0f / rs[0];
    float* orow = out + ((size_t)b * NSTEPS + step) * VV;
    for (int v = tid; v < VV; v += 256) orow[v] = expf(lrow[(size_t)b * VV + v] - mx) * inv;
    if (tid == 0) y[b] = ri[0];
}

// ---------------- host launch ----------------
extern "C" void kernel_launch(void* const* d_in, const int* in_sizes, int n_in,
                              void* d_out, int out_size, void* d_ws, size_t ws_size,
                              hipStream_t stream)
{
    const int*   source  = (const int*)d_in[0];
    const float* emb_enc = (const float*)d_in[1];
    const float* Wx_e    = (const float*)d_in[2];
    const float* Wh_e    = (const float*)d_in[3];
    const float* b_e     = (const float*)d_in[4];
    const float* emb_dec = (const float*)d_in[5];
    const float* Wx_d    = (const float*)d_in[6];
    const float* Wh_d    = (const float*)d_in[7];
    const float* b_d     = (const float*)d_in[8];
    const float* W_a     = (const float*)d_in[9];
    const float* W_c     = (const float*)d_in[10];
    const float* b_c     = (const float*)d_in[11];
    const float* W_out   = (const float*)d_in[12];
    const float* b_out   = (const float*)d_in[13];
    float* out = (float*)d_out;

    // workspace layout (floats). lpart aliases zpart, lrow aliases wcpart (disjoint lifetimes).
    float* ws = (float*)d_ws;
    float* h    = ws;                    // 32768
    float* c    = h + 32768;             // 32768
    float* hs   = c + 32768;             // 32*64*1024 = 2097152
    float* hs_a = hs + 2097152;          // 2097152
    float* ctxb = hs_a + 2097152;        // 32768
    float* htb  = ctxb + 32768;          // 32768
    float* zpart  = htb + 32768;         // 32*32*4096 = 4194304 (also lpart: 4*32*32000 = 4096000)
    float* wcpart = zpart + 4194304;     // 64*32*1024 = 2097152 (also lrow: 32*32000 = 1024000)
    int*   y = (int*)(wcpart + 2097152); // 32 ints
    float* lpart = zpart;
    float* lrow  = wcpart;

    init_hc<<<128, 256, 0, stream>>>(h, c);

    // ---- encoder: 64 steps ----
    for (int s = 0; s < SS; s++) {
        // z = [emb_enc[src[:,s]] ; h] @ [Wx_e ; Wh_e]  -> 32 k-slices of 64
        gemm_skinny<64><<<256, 256, 0, stream>>>(
            nullptr, h, source + s, SS, emb_enc, Wx_e, Wh_e, 1024, 4096, 8, zpart);
        enc_gates<<<128, 256, 0, stream>>>(zpart, 32, b_e, h, c, hs, s);
    }

    // hs_a = hs @ W_a; y = BOS
    hsa_kernel<<<512, 256, 0, stream>>>(hs, W_a, hs_a, y);

    // ---- decoder: 64 steps ----
    for (int t = 0; t < NSTEPS; t++) {
        gemm_skinny<64><<<256, 256, 0, stream>>>(
            nullptr, h, y, 1, emb_dec, Wx_d, Wh_d, 1024, 4096, 8, zpart);
        attn_gates<<<32, 256, 0, stream>>>(zpart, 32, b_d, y, h, c, hs_a, hs, source, ctxb);
        // ht_pre = [ctx ; h2] @ W_c -> 64 k-slices of 32
        gemm_skinny<32><<<128, 256, 0, stream>>>(
            ctxb, h, nullptr, 0, nullptr, W_c, nullptr, 2048, 1024, 2, wcpart);
        ht_reduce<<<128, 256, 0, stream>>>(wcpart, 64, b_c, htb);
        // logits = ht @ W_out -> 4 k-slices of 256, 63 j-blocks
        gemm_skinny<256><<<252, 256, 0, stream>>>(
            htb, nullptr, nullptr, 0, nullptr, W_out, nullptr, 1024, 32000, 63, lpart);
        softmax_out<<<32, 256, 0, stream>>>(lpart, b_out, lrow, out, y, t);
    }
}